// Round 5
// baseline (1499.499 us; speedup 1.0000x reference)
//
#include <hip/hip_runtime.h>
#include <float.h>

#define NB 16
#define NP 1024
#define NROW (NB*NP)

// ---------------------------------------------------------------- init
__global__ void k_init(float* colsum, float* colsq, float* pmax, float* pmin) {
    int i = blockIdx.x * 256 + threadIdx.x;          // grid 256 -> i < 65536
    if (i < 1024) { colsum[i] = 0.f; colsq[i] = 0.f; }
    pmax[i] = -FLT_MAX;
    pmin[i] =  FLT_MAX;
}

// ---------------------------------------------------------------- weight prep
// wc[kk, c] = (c<dout) ? Wtop-Wbot : Wbot ;  b2 = [b, 0]
__global__ void k_prep(const float* __restrict__ W, const float* __restrict__ b,
                       float* __restrict__ wc, float* __restrict__ b2, int d, int dout) {
    int n2 = 2 * dout;
    int i = blockIdx.x * 256 + threadIdx.x;
    if (i < d * n2) {
        int kk = i / n2, c = i % n2;
        wc[i] = (c < dout) ? (W[kk * dout + c] - W[(kk + d) * dout + c])
                           : W[(kk + d) * dout + (c - dout)];
    }
    if (i < n2) b2[i] = (i < dout) ? b[i] : 0.f;
}

// ---------------------------------------------------------------- squared norms
__global__ void k_sqnorm(const float* __restrict__ x, int stride, int D, float* __restrict__ sq) {
    int row = blockIdx.x * 4 + (threadIdx.x >> 6);
    int lane = threadIdx.x & 63;
    const float* xr = x + (size_t)row * stride;
    float s = 0.f;
    for (int kk = lane; kk < D; kk += 64) { float v = xr[kk]; s += v * v; }
    for (int o = 32; o; o >>= 1) s += __shfl_down(s, o);
    if (lane == 0) sq[row] = s;
}

// ---------------------------------------------------------------- kNN (top-20 smallest key = sqj - 2*dot)
// block 256 = 4 waves; 64 rows per block (lane = row), each wave handles 1/4 of each 32-j tile.
template<int D>
__global__ __launch_bounds__(256) void k_knn(const float* __restrict__ x, int stride,
                                             const float* __restrict__ sq, int* __restrict__ idxout) {
    constexpr int TJ = 32;                 // j-tile size
    constexpr int XJ = TJ * D;
    constexpr int MERGE = 20 * 64 * 2;
    constexpr int SM = (XJ > MERGE) ? XJ : MERGE;
    __shared__ __align__(16) float smem[SM];
    __shared__ float sqj[TJ];
    __shared__ float topd[20 * 256];              // 20KB
    __shared__ unsigned short topi[20 * 256];     // 10KB (j < 1024 fits u16)

    const int b = blockIdx.y;
    const int r0 = blockIdx.x * 64;
    const int tid = threadIdx.x;
    const int wave = tid >> 6, lane = tid & 63;
    const int row = r0 + lane;

    const float* xr = x + (size_t)(b * NP + row) * stride;
    float xi[D];
#pragma unroll
    for (int kk = 0; kk < D; kk++) xi[kk] = xr[kk];

#pragma unroll
    for (int t = 0; t < 20; t++) topd[t * 256 + tid] = FLT_MAX;
    float curmax = FLT_MAX; int maxpos = 0;

    for (int jt = 0; jt < NP / TJ; jt++) {
        __syncthreads();
        if constexpr (D % 4 == 0) {
            constexpr int D4 = D / 4;
            float4* xj4 = (float4*)smem;
            for (int e = tid; e < TJ * D4; e += 256) {
                int jj = e / D4, kq = e % D4;
                xj4[e] = *(const float4*)(x + (size_t)(b * NP + jt * TJ + jj) * stride + kq * 4);
            }
        } else {
            for (int e = tid; e < TJ * D; e += 256) {
                int jj = e / D, kk = e % D;
                smem[e] = x[(size_t)(b * NP + jt * TJ + jj) * stride + kk];
            }
        }
        if (tid < TJ) sqj[tid] = sq[b * NP + jt * TJ + tid];
        __syncthreads();

#pragma unroll 1
        for (int u = 0; u < TJ / 4; u++) {
            int jj = wave * (TJ / 4) + u;
            float acc = 0.f;
            if constexpr (D % 4 == 0) {
                const float4* xv = ((const float4*)smem) + jj * (D / 4);
#pragma unroll
                for (int kq = 0; kq < D / 4; kq++) {
                    float4 v = xv[kq];
                    acc += xi[4 * kq] * v.x + xi[4 * kq + 1] * v.y + xi[4 * kq + 2] * v.z + xi[4 * kq + 3] * v.w;
                }
            } else {
#pragma unroll
                for (int kk = 0; kk < D; kk++) acc += xi[kk] * smem[jj * D + kk];
            }
            float key = sqj[jj] - 2.f * acc;
            if (key < curmax) {
                topd[maxpos * 256 + tid] = key;
                topi[maxpos * 256 + tid] = (unsigned short)(jt * TJ + jj);
                float m = -FLT_MAX; int mp = 0;
#pragma unroll
                for (int t = 0; t < 20; t++) {
                    float v = topd[t * 256 + tid];
                    if (v > m) { m = v; mp = t; }
                }
                curmax = m; maxpos = mp;
            }
        }
    }
    __syncthreads();

    if (tid < 64) {   // merge 4 per-wave lists of 20 -> final 20
        float* fd = smem;
        int* fi = (int*)(smem + 20 * 64);
        float fm = FLT_MAX; int fp = 0;
#pragma unroll
        for (int t = 0; t < 20; t++) fd[t * 64 + tid] = FLT_MAX;
        for (int w = 0; w < 4; w++) {
#pragma unroll 1
            for (int t = 0; t < 20; t++) {
                float key = topd[t * 256 + w * 64 + tid];
                if (key < fm) {
                    fd[fp * 64 + tid] = key;
                    fi[fp * 64 + tid] = (int)topi[t * 256 + w * 64 + tid];
                    float m = -FLT_MAX; int mp = 0;
#pragma unroll
                    for (int t2 = 0; t2 < 20; t2++) {
                        float v = fd[t2 * 64 + tid];
                        if (v > m) { m = v; mp = t2; }
                    }
                    fm = m; fp = mp;
                }
            }
        }
#pragma unroll
        for (int t = 0; t < 20; t++)
            idxout[(size_t)(b * NP + r0 + tid) * 20 + t] = fi[t * 64 + tid];
    }
}

// ---------------------------------------------------------------- p/q GEMM:  pq = x @ wc + b2
#define FMA16(a, bv) do { \
    acc[0].x += (a).x*(bv).x; acc[0].y += (a).x*(bv).y; acc[0].z += (a).x*(bv).z; acc[0].w += (a).x*(bv).w; \
    acc[1].x += (a).y*(bv).x; acc[1].y += (a).y*(bv).y; acc[1].z += (a).y*(bv).z; acc[1].w += (a).y*(bv).w; \
    acc[2].x += (a).z*(bv).x; acc[2].y += (a).z*(bv).y; acc[2].z += (a).z*(bv).z; acc[2].w += (a).z*(bv).w; \
    acc[3].x += (a).w*(bv).x; acc[3].y += (a).w*(bv).y; acc[3].z += (a).w*(bv).z; acc[3].w += (a).w*(bv).w; \
} while (0)

template<int D, int DOUT>
__global__ __launch_bounds__(256) void k_gemm_pq(const float* __restrict__ x, int stride,
                                                 const float* __restrict__ wc, const float* __restrict__ b2,
                                                 float* __restrict__ pq) {
    constexpr int N2 = 2 * DOUT;
    constexpr int KC = (D > 64) ? 64 : D;      // K-chunk keeps LDS small
    __shared__ __align__(16) float At[KC * 68];
    __shared__ __align__(16) float Bs[KC * 64];
    const int tid = threadIdx.x;
    const int tx = tid & 15, ty = tid >> 4;
    const int r0 = blockIdx.x * 64;
    const int c0 = blockIdx.y * 64;

    float4 acc[4] = {};
    for (int k0 = 0; k0 < D; k0 += KC) {
        __syncthreads();
        if constexpr (KC % 4 == 0) {
            constexpr int K4 = KC / 4;
            for (int e = tid; e < 64 * K4; e += 256) {
                int rr = e / K4, kq = e % K4;
                float4 v = *(const float4*)(x + (size_t)(r0 + rr) * stride + k0 + kq * 4);
                At[(4 * kq + 0) * 68 + rr] = v.x;
                At[(4 * kq + 1) * 68 + rr] = v.y;
                At[(4 * kq + 2) * 68 + rr] = v.z;
                At[(4 * kq + 3) * 68 + rr] = v.w;
            }
        } else {
            for (int e = tid; e < 64 * KC; e += 256) {
                int rr = e / KC, kk = e % KC;
                At[kk * 68 + rr] = x[(size_t)(r0 + rr) * stride + k0 + kk];
            }
        }
        for (int e = tid; e < KC * 16; e += 256) {
            int kk = e / 16, cq = e % 16;
            *(float4*)&Bs[kk * 64 + cq * 4] = *(const float4*)(wc + (size_t)(k0 + kk) * N2 + c0 + cq * 4);
        }
        __syncthreads();
#pragma unroll 8
        for (int kk = 0; kk < KC; kk++) {
            float4 a = *(const float4*)&At[kk * 68 + ty * 4];
            float4 bv = *(const float4*)&Bs[kk * 64 + tx * 4];
            FMA16(a, bv);
        }
    }
    float4 bias = *(const float4*)(b2 + c0 + tx * 4);
#pragma unroll
    for (int ri = 0; ri < 4; ri++) {
        float4 o;
        o.x = acc[ri].x + bias.x; o.y = acc[ri].y + bias.y;
        o.z = acc[ri].z + bias.z; o.w = acc[ri].w + bias.w;
        *(float4*)(pq + (size_t)(r0 + ty * 4 + ri) * N2 + c0 + tx * 4) = o;
    }
}

// ---------------------------------------------------------------- gather + max over 20 neighbors
__global__ void k_gather(const float* __restrict__ pq, const int* __restrict__ idx,
                         float* __restrict__ cat_, int log2dout, int off) {
    int gid = blockIdx.x * 256 + threadIdx.x;
    int dout = 1 << log2dout;
    int row = gid >> log2dout;
    int c = gid & (dout - 1);
    int b = row >> 10;
    int s2 = dout * 2;
    const float* qb = pq + (size_t)(b << 10) * s2 + dout + c;
    const int* ip = idx + (size_t)row * 20;
    float m = -FLT_MAX;
#pragma unroll
    for (int t = 0; t < 20; t++) {
        int j = ip[t];
        m = fmaxf(m, qb[(size_t)j * s2]);
    }
    cat_[(size_t)row * 512 + off + c] = pq[(size_t)row * s2 + c] + m;
}

// ---------------------------------------------------------------- fused linear: y = cat@Wl + bl, col stats + per-(b,c) max/min
__global__ __launch_bounds__(256) void k_fused_lin(const float* __restrict__ cat_, const float* __restrict__ Wl,
                                                   const float* __restrict__ bl,
                                                   float* colsum, float* colsq, float* pmax, float* pmin) {
    __shared__ __align__(16) float At[32 * 68];
    __shared__ __align__(16) float Bs[32 * 64];
    __shared__ float red[16 * 64];
    const int tid = threadIdx.x;
    const int tx = tid & 15, ty = tid >> 4;
    const int ct = blockIdx.x, b = blockIdx.y, rs = blockIdx.z;
    const int c0 = ct * 64;

    float4 blv = *(const float4*)(bl + c0 + tx * 4);
    float4 s = {0, 0, 0, 0}, ss = {0, 0, 0, 0};
    float4 mx = {-FLT_MAX, -FLT_MAX, -FLT_MAX, -FLT_MAX};
    float4 mn = {FLT_MAX, FLT_MAX, FLT_MAX, FLT_MAX};

    for (int rt = 0; rt < 4; rt++) {
        int r0 = b * 1024 + rs * 256 + rt * 64;
        float4 acc[4] = {};
        for (int kt = 0; kt < 16; kt++) {
            __syncthreads();
            for (int e = tid; e < 512; e += 256) {
                int rr = e >> 3, kq = e & 7;
                float4 v = *(const float4*)(cat_ + (size_t)(r0 + rr) * 512 + kt * 32 + kq * 4);
                At[(4 * kq + 0) * 68 + rr] = v.x;
                At[(4 * kq + 1) * 68 + rr] = v.y;
                At[(4 * kq + 2) * 68 + rr] = v.z;
                At[(4 * kq + 3) * 68 + rr] = v.w;
            }
            for (int e = tid; e < 512; e += 256) {
                int kk = e >> 4, cq = e & 15;
                *(float4*)&Bs[kk * 64 + cq * 4] = *(const float4*)(Wl + (size_t)(kt * 32 + kk) * 1024 + c0 + cq * 4);
            }
            __syncthreads();
#pragma unroll 8
            for (int kk = 0; kk < 32; kk++) {
                float4 a = *(const float4*)&At[kk * 68 + ty * 4];
                float4 bv = *(const float4*)&Bs[kk * 64 + tx * 4];
                FMA16(a, bv);
            }
        }
#pragma unroll
        for (int ri = 0; ri < 4; ri++) {
            float yx = acc[ri].x + blv.x, yy = acc[ri].y + blv.y;
            float yz = acc[ri].z + blv.z, yw = acc[ri].w + blv.w;
            s.x += yx; ss.x += yx * yx; mx.x = fmaxf(mx.x, yx); mn.x = fminf(mn.x, yx);
            s.y += yy; ss.y += yy * yy; mx.y = fmaxf(mx.y, yy); mn.y = fminf(mn.y, yy);
            s.z += yz; ss.z += yz * yz; mx.z = fmaxf(mx.z, yz); mn.z = fminf(mn.z, yz);
            s.w += yw; ss.w += yw * yw; mx.w = fmaxf(mx.w, yw); mn.w = fminf(mn.w, yw);
        }
    }

    // block reductions over the 16 ty groups
    float rsum = 0.f, rss = 0.f, rmx = -FLT_MAX, rmn = FLT_MAX;
    __syncthreads(); *(float4*)&red[ty * 64 + tx * 4] = s;  __syncthreads();
    if (tid < 64) for (int t = 0; t < 16; t++) rsum += red[t * 64 + tid];
    __syncthreads(); *(float4*)&red[ty * 64 + tx * 4] = ss; __syncthreads();
    if (tid < 64) for (int t = 0; t < 16; t++) rss += red[t * 64 + tid];
    __syncthreads(); *(float4*)&red[ty * 64 + tx * 4] = mx; __syncthreads();
    if (tid < 64) for (int t = 0; t < 16; t++) rmx = fmaxf(rmx, red[t * 64 + tid]);
    __syncthreads(); *(float4*)&red[ty * 64 + tx * 4] = mn; __syncthreads();
    if (tid < 64) for (int t = 0; t < 16; t++) rmn = fminf(rmn, red[t * 64 + tid]);

    if (tid < 64) {
        int c = c0 + tid;
        atomicAdd(&colsum[c], rsum);
        atomicAdd(&colsq[c], rss);
        pmax[(size_t)(rs * 16 + b) * 1024 + c] = rmx;
        pmin[(size_t)(rs * 16 + b) * 1024 + c] = rmn;
    }
}

// ---------------------------------------------------------------- BN + leaky + pool (commuted through max/min)
__global__ void k_bnpool(const float* colsum, const float* colsq,
                         const float* pmax, const float* pmin,
                         const float* __restrict__ gl, const float* __restrict__ betal,
                         float* __restrict__ pooled) {
    int gid = blockIdx.x * 256 + threadIdx.x;   // 16384
    int c = gid & 1023, b = gid >> 10;
    float mean = colsum[c] * (1.f / 16384.f);
    float var = colsq[c] * (1.f / 16384.f) - mean * mean;
    float a = gl[c] * rsqrtf(var + 1e-5f);
    float d = betal[c] - mean * a;
    float vmx = -FLT_MAX, vmn = FLT_MAX;
#pragma unroll
    for (int rs = 0; rs < 4; rs++) {
        vmx = fmaxf(vmx, pmax[(size_t)(rs * 16 + b) * 1024 + c]);
        vmn = fminf(vmn, pmin[(size_t)(rs * 16 + b) * 1024 + c]);
    }
    float v = a * ((a >= 0.f) ? vmx : vmn) + d;
    pooled[gid] = v > 0.f ? v : 0.2f * v;
}

// ---------------------------------------------------------------- MLP stage 1: z = pooled@Wm1+bm1, BN over 16 rows, leaky
__global__ __launch_bounds__(256) void k_mlp1(const float* __restrict__ pooled, const float* __restrict__ Wm1,
                                              const float* __restrict__ bm1, const float* __restrict__ gm1,
                                              const float* __restrict__ betam1, float* __restrict__ hbuf) {
    int tid = threadIdx.x;
    int r = tid >> 4, cl = tid & 15;
    int c = blockIdx.x * 16 + cl;
    float z = bm1[c];
    const float* pr = pooled + (size_t)r * 1024;
    for (int kk = 0; kk < 1024; kk++) z += pr[kk] * Wm1[(size_t)kk * 512 + c];
    __shared__ float zb[16 * 16];
    zb[r * 16 + cl] = z;
    __syncthreads();
    float sm = 0.f, sq = 0.f;
#pragma unroll
    for (int rr = 0; rr < 16; rr++) { float v = zb[rr * 16 + cl]; sm += v; sq += v * v; }
    float mean = sm * (1.f / 16.f);
    float var = sq * (1.f / 16.f) - mean * mean;
    float h = gm1[c] * (z - mean) * rsqrtf(var + 1e-5f) + betam1[c];
    hbuf[(size_t)r * 512 + c] = h > 0.f ? h : 0.2f * h;
}

// ---------------------------------------------------------------- MLP stage 2
__global__ void k_mlp2(const float* __restrict__ hbuf, const float* __restrict__ Wm2,
                       const float* __restrict__ bm2, float* __restrict__ out) {
    int gid = blockIdx.x * 256 + threadIdx.x;
    if (gid >= 640) return;
    int r = gid / 40, c = gid % 40;
    float o = bm2[c];
    const float* hr = hbuf + (size_t)r * 512;
    for (int kk = 0; kk < 512; kk++) o += hr[kk] * Wm2[(size_t)kk * 40 + c];
    out[gid] = o;
}

// ----------------------------------------------------------------
extern "C" void kernel_launch(void* const* d_in, const int* in_sizes, int n_in,
                              void* d_out, int out_size, void* d_ws, size_t ws_size,
                              hipStream_t stream) {
    const float* pos = (const float*)d_in[0];
    const float* W1 = (const float*)d_in[2];
    const float* b1 = (const float*)d_in[3];
    const float* W2 = (const float*)d_in[4];
    const float* b2 = (const float*)d_in[5];
    const float* W3 = (const float*)d_in[6];
    const float* b3 = (const float*)d_in[7];
    const float* W4 = (const float*)d_in[8];
    const float* b4 = (const float*)d_in[9];
    const float* Wl = (const float*)d_in[10];
    const float* bl = (const float*)d_in[11];
    const float* gl = (const float*)d_in[12];
    const float* betal = (const float*)d_in[13];
    const float* Wm1 = (const float*)d_in[14];
    const float* bm1 = (const float*)d_in[15];
    const float* gm1 = (const float*)d_in[16];
    const float* betam1 = (const float*)d_in[17];
    const float* Wm2 = (const float*)d_in[18];
    const float* bm2 = (const float*)d_in[19];
    float* out = (float*)d_out;

    float* ws = (float*)d_ws;
    float* cat_ = ws;                                   // 16384*512
    float* pq = cat_ + (size_t)NROW * 512;              // 16384*512
    int* idx = (int*)(pq + (size_t)NROW * 512);         // 16384*20
    float* sqb = (float*)(idx + NROW * 20);             // 16384
    float* wc1 = sqb + NROW;
    float* wc2 = wc1 + 3 * 128;
    float* wc3 = wc2 + 64 * 128;
    float* wc4 = wc3 + 64 * 256;
    float* bb1 = wc4 + 128 * 512;
    float* bb2 = bb1 + 128;
    float* bb3 = bb2 + 128;
    float* bb4 = bb3 + 256;
    float* colsum = bb4 + 512;
    float* colsq = colsum + 1024;
    float* pmax = colsq + 1024;                         // 4*16384
    float* pmin = pmax + 4 * NROW;                      // 4*16384
    float* pooled = pmin + 4 * NROW;                    // 16384
    float* hbuf = pooled + NROW;                        // 8192
    size_t need = (size_t)((hbuf + 16 * 512) - ws) * sizeof(float);
    if (ws_size < need) return;                         // clean fail if ws too small

    k_init<<<256, 256, 0, stream>>>(colsum, colsq, pmax, pmin);
    k_prep<<<256, 256, 0, stream>>>(W1, b1, wc1, bb1, 3, 64);
    k_prep<<<256, 256, 0, stream>>>(W2, b2, wc2, bb2, 64, 64);
    k_prep<<<256, 256, 0, stream>>>(W3, b3, wc3, bb3, 64, 128);
    k_prep<<<256, 256, 0, stream>>>(W4, b4, wc4, bb4, 128, 256);

    // layer 1 (D=3 -> 64)
    k_sqnorm<<<4096, 256, 0, stream>>>(pos, 3, 3, sqb);
    k_knn<3><<<dim3(16, 16), 256, 0, stream>>>(pos, 3, sqb, idx);
    k_gemm_pq<3, 64><<<dim3(256, 2), 256, 0, stream>>>(pos, 3, wc1, bb1, pq);
    k_gather<<<4096, 256, 0, stream>>>(pq, idx, cat_, 6, 0);
    // layer 2 (64 -> 64)
    k_sqnorm<<<4096, 256, 0, stream>>>(cat_, 512, 64, sqb);
    k_knn<64><<<dim3(16, 16), 256, 0, stream>>>(cat_, 512, sqb, idx);
    k_gemm_pq<64, 64><<<dim3(256, 2), 256, 0, stream>>>(cat_, 512, wc2, bb2, pq);
    k_gather<<<4096, 256, 0, stream>>>(pq, idx, cat_, 6, 64);
    // layer 3 (64 -> 128)
    k_sqnorm<<<4096, 256, 0, stream>>>(cat_ + 64, 512, 64, sqb);
    k_knn<64><<<dim3(16, 16), 256, 0, stream>>>(cat_ + 64, 512, sqb, idx);
    k_gemm_pq<64, 128><<<dim3(256, 4), 256, 0, stream>>>(cat_ + 64, 512, wc3, bb3, pq);
    k_gather<<<8192, 256, 0, stream>>>(pq, idx, cat_, 7, 128);
    // layer 4 (128 -> 256)
    k_sqnorm<<<4096, 256, 0, stream>>>(cat_ + 128, 512, 128, sqb);
    k_knn<128><<<dim3(16, 16), 256, 0, stream>>>(cat_ + 128, 512, sqb, idx);
    k_gemm_pq<128, 256><<<dim3(256, 8), 256, 0, stream>>>(cat_ + 128, 512, wc4, bb4, pq);
    k_gather<<<16384, 256, 0, stream>>>(pq, idx, cat_, 8, 256);

    k_fused_lin<<<dim3(16, 16, 4), 256, 0, stream>>>(cat_, Wl, bl, colsum, colsq, pmax, pmin);
    k_bnpool<<<64, 256, 0, stream>>>(colsum, colsq, pmax, pmin, gl, betal, pooled);
    k_mlp1<<<32, 256, 0, stream>>>(pooled, Wm1, bm1, gm1, betam1, hbuf);
    k_mlp2<<<3, 256, 0, stream>>>(hbuf, Wm2, bm2, out);
}